// Round 2
// baseline (587.217 us; speedup 1.0000x reference)
//
#include <hip/hip_runtime.h>
#include <hip/hip_bf16.h>
#include <stdint.h>

// Problem constants: M=512, P=256, B=128, T=1024
#define NB   128
#define NT   1024
#define NM   512
#define NP   256

typedef __attribute__((ext_vector_type(8))) short bf16x8;
typedef __attribute__((ext_vector_type(4))) float f32x4;

// pack two f32 -> two bf16 in one u32 (round-half-up; bias << bf16 ulp, fine vs 1.7e-4 threshold)
__device__ __forceinline__ uint32_t bfpair(float a, float b) {
    uint32_t ua = __float_as_uint(a) + 0x8000u;
    uint32_t ub = __float_as_uint(b) + 0x8000u;
    // v_perm_b32: sel bytes 0..3 pick from src1(ua), 4..7 from src0(ub)
    return __builtin_amdgcn_perm(ub, ua, 0x07060302u);
}

__device__ __forceinline__ bf16x8 pack8(float4 f0, float4 f1) {
    union { bf16x8 v; uint32_t u[4]; } r;
    r.u[0] = bfpair(f0.x, f0.y);
    r.u[1] = bfpair(f0.z, f0.w);
    r.u[2] = bfpair(f1.x, f1.y);
    r.u[3] = bfpair(f1.z, f1.w);
    return r.v;
}

__device__ __forceinline__ float fast_tanh(float x) {
    float e = __expf(2.0f * x);                       // inf-safe: e->inf => tanh->1, e->0 => -1
    return 1.0f - 2.0f * __builtin_amdgcn_rcpf(e + 1.0f);
}

// ---------- Kernel 1: convert U (512x512 f32 row-major [n][m]) -> bf16 ----------
__global__ void cvt_u_kernel(const float* __restrict__ U, unsigned short* __restrict__ Ub) {
    int idx = blockIdx.x * blockDim.x + threadIdx.x;   // 65536 threads, 1 float4 each
    float4 u = reinterpret_cast<const float4*>(U)[idx];
    uint32_t lo = bfpair(u.x, u.y);
    uint32_t hi = bfpair(u.z, u.w);
    reinterpret_cast<uint2*>(Ub)[idx] = make_uint2(lo, hi);
}

// ---------- Kernel 2: wq[b][n] = sum_c q[b][c] * W[n][c] (fp32, exact) ----------
__global__ void wq_kernel(const float* __restrict__ d_t, const float* __restrict__ s_t,
                          const float* __restrict__ W, float* __restrict__ wq) {
    int g = blockIdx.x * blockDim.x + threadIdx.x;     // 0..65535
    int b = g >> 9;
    int n = g & 511;
    const float* Wn = W + (size_t)n * 512;
    const float* dt = d_t + (size_t)b * NP;
    const float* st = s_t + (size_t)b * NP;
    float s = 0.f;
    #pragma unroll 4
    for (int c = 0; c < NP; c += 4) {
        float4 w0 = *reinterpret_cast<const float4*>(Wn + c);
        float4 q0 = *reinterpret_cast<const float4*>(dt + c);
        s += w0.x * q0.x + w0.y * q0.y + w0.z * q0.z + w0.w * q0.w;
        float4 w1 = *reinterpret_cast<const float4*>(Wn + NP + c);
        float4 q1 = *reinterpret_cast<const float4*>(st + c);
        s += w1.x * q1.x + w1.y * q1.y + w1.z * q1.z + w1.w * q1.w;
    }
    wq[g] = s;
}

// ---------- Kernel 3: no-LDS GEMM + epilogue ----------
// WG = 4 waves; wave w: t-rows [t0, t0+64) x n [w*128, w*128+128)
// A frags: per-lane direct global loads of H (8 contig f32 -> pack bf16)
// B frags: per-lane direct global dwordx4 of L2-resident Ub
// No __syncthreads in the K-loop; only one barrier before the epilogue reduce.
__global__ __launch_bounds__(256, 2)
void score_kernel(const float* __restrict__ H, const unsigned short* __restrict__ Ub,
                  const float* __restrict__ wq, const float* __restrict__ v_d,
                  float* __restrict__ out) {
    __shared__ float s_score[64];

    const int tid  = threadIdx.x;
    const int b    = blockIdx.y;
    const int t0   = blockIdx.x * 64;
    const int lane = tid & 63;
    const int w    = tid >> 6;      // n-quadrant
    const int lr   = lane & 15;
    const int lq   = lane >> 4;

    // per-lane base pointers
    const float* pA = H + ((size_t)b * NT + t0 + lr) * NM + lq * 8;
    const unsigned short* pB = Ub + ((size_t)(w * 128 + lr)) * NM + lq * 8;

    f32x4 acc[4][8];
    #pragma unroll
    for (int i = 0; i < 4; ++i)
        #pragma unroll
        for (int j = 0; j < 8; ++j)
            acc[i][j] = (f32x4){0.f, 0.f, 0.f, 0.f};

    #pragma unroll 2
    for (int kk = 0; kk < 16; ++kk) {
        const int k0 = kk * 32;

        bf16x8 a[4];
        #pragma unroll
        for (int i = 0; i < 4; ++i) {
            const float* ap = pA + (size_t)i * 16 * NM + k0;
            float4 f0 = *reinterpret_cast<const float4*>(ap);
            float4 f1 = *reinterpret_cast<const float4*>(ap + 4);
            a[i] = pack8(f0, f1);
        }

        bf16x8 bq[8];
        #pragma unroll
        for (int j = 0; j < 8; ++j)
            bq[j] = *reinterpret_cast<const bf16x8*>(pB + (size_t)j * 16 * NM + k0);

        #pragma unroll
        for (int i = 0; i < 4; ++i)
            #pragma unroll
            for (int j = 0; j < 8; ++j)
                acc[i][j] = __builtin_amdgcn_mfma_f32_16x16x32_bf16(a[i], bq[j], acc[i][j], 0, 0, 0);
    }

    // Epilogue: C/D layout col(n) = lane&15 offsetted by j*16+w*128, row(t) = lq*4 + reg
    if (tid < 64) s_score[tid] = 0.f;
    __syncthreads();

    const float* wqb = wq + (size_t)b * NM;
    float vv[8], wv[8];
    #pragma unroll
    for (int j = 0; j < 8; ++j) {
        int n = w * 128 + j * 16 + lr;
        vv[j] = v_d[n];
        wv[j] = wqb[n];
    }
    #pragma unroll
    for (int i = 0; i < 4; ++i) {
        #pragma unroll
        for (int r = 0; r < 4; ++r) {
            float s = 0.f;
            #pragma unroll
            for (int j = 0; j < 8; ++j)
                s += vv[j] * fast_tanh(wv[j] + acc[i][j][r]);
            #pragma unroll
            for (int off = 1; off < 16; off <<= 1)
                s += __shfl_xor(s, off, 64);
            if (lr == 0) atomicAdd(&s_score[i * 16 + lq * 4 + r], s);
        }
    }
    __syncthreads();
    if (tid < 64) out[(size_t)b * NT + t0 + tid] = s_score[tid];
}

// ---------- Kernel 4: softmax over T=1024, in place, one WG per b ----------
__global__ void softmax_kernel(float* __restrict__ out) {
    const int b   = blockIdx.x;
    const int tid = threadIdx.x;          // 256 threads x 4 elems
    float* p = out + (size_t)b * NT;
    float4 v = reinterpret_cast<float4*>(p)[tid];
    float m = fmaxf(fmaxf(v.x, v.y), fmaxf(v.z, v.w));
    #pragma unroll
    for (int off = 32; off >= 1; off >>= 1)
        m = fmaxf(m, __shfl_xor(m, off, 64));
    __shared__ float red[8];
    const int wv = tid >> 6;
    if ((tid & 63) == 0) red[wv] = m;
    __syncthreads();
    m = fmaxf(fmaxf(red[0], red[1]), fmaxf(red[2], red[3]));
    float e0 = __expf(v.x - m), e1 = __expf(v.y - m);
    float e2 = __expf(v.z - m), e3 = __expf(v.w - m);
    float s = e0 + e1 + e2 + e3;
    #pragma unroll
    for (int off = 32; off >= 1; off >>= 1)
        s += __shfl_xor(s, off, 64);
    if ((tid & 63) == 0) red[4 + wv] = s;
    __syncthreads();
    s = red[4] + red[5] + red[6] + red[7];
    float inv = 1.f / s;
    float4 o;
    o.x = e0 * inv; o.y = e1 * inv; o.z = e2 * inv; o.w = e3 * inv;
    reinterpret_cast<float4*>(p)[tid] = o;
}

extern "C" void kernel_launch(void* const* d_in, const int* in_sizes, int n_in,
                              void* d_out, int out_size, void* d_ws, size_t ws_size,
                              hipStream_t stream) {
    const float* d_t = (const float*)d_in[0];
    const float* s_t = (const float*)d_in[1];
    const float* H   = (const float*)d_in[2];
    // d_in[3] = T (scalar, 1024) — shapes hard-coded
    const float* W_d = (const float*)d_in[4];
    const float* U_d = (const float*)d_in[5];
    const float* v_d = (const float*)d_in[6];
    float* out = (float*)d_out;

    unsigned short* Ub = (unsigned short*)d_ws;              // 512 KB bf16 U
    float* wq = (float*)((char*)d_ws + 512 * 1024);          // 256 KB fp32 wq

    cvt_u_kernel<<<256, 256, 0, stream>>>(U_d, Ub);
    wq_kernel<<<256, 256, 0, stream>>>(d_t, s_t, W_d, wq);
    score_kernel<<<dim3(NT / 64, NB), 256, 0, stream>>>(H, Ub, wq, v_d, out);
    softmax_kernel<<<NB, 256, 0, stream>>>(out);
}

// Round 3
// 508.204 us; speedup vs baseline: 1.1555x; 1.1555x over previous
//
#include <hip/hip_runtime.h>
#include <hip/hip_bf16.h>
#include <stdint.h>

// Problem constants: M=512, P=256, B=128, T=1024
#define NB   128
#define NT   1024
#define NM   512
#define NP   256

typedef __attribute__((ext_vector_type(8))) short bf16x8;
typedef __attribute__((ext_vector_type(4))) float f32x4;

// pack two f32 -> two bf16 in one u32 (round-half-up; bias << bf16 ulp)
__device__ __forceinline__ uint32_t bfpair(float a, float b) {
    uint32_t ua = __float_as_uint(a) + 0x8000u;
    uint32_t ub = __float_as_uint(b) + 0x8000u;
    return __builtin_amdgcn_perm(ub, ua, 0x07060302u);
}

__device__ __forceinline__ float fast_tanh(float x) {
    float e = __expf(2.0f * x);                       // inf-safe
    return 1.0f - 2.0f * __builtin_amdgcn_rcpf(e + 1.0f);
}

// ---------- prep: blocks 0..255 convert U -> bf16; blocks 256..383 compute wq ----------
__global__ void prep_kernel(const float* __restrict__ U, unsigned short* __restrict__ Ub,
                            const float* __restrict__ d_t, const float* __restrict__ s_t,
                            const float* __restrict__ W, float* __restrict__ wq) {
    if (blockIdx.x < 256) {
        int idx = blockIdx.x * 256 + threadIdx.x;          // 65536 threads, 1 float4 each
        float4 u = reinterpret_cast<const float4*>(U)[idx];
        reinterpret_cast<uint2*>(Ub)[idx] = make_uint2(bfpair(u.x, u.y), bfpair(u.z, u.w));
    } else {
        int g = (blockIdx.x - 256) * 512 + threadIdx.x * 2; // 2 outputs per thread -> 65536
        int b = g >> 9;
        const float* dt = d_t + (size_t)b * NP;
        const float* st = s_t + (size_t)b * NP;
        #pragma unroll
        for (int e = 0; e < 2; ++e) {
            int n = (g + e) & 511;
            const float* Wn = W + (size_t)n * 512;
            float s = 0.f;
            #pragma unroll 4
            for (int c = 0; c < NP; c += 4) {
                float4 w0 = *reinterpret_cast<const float4*>(Wn + c);
                float4 q0 = *reinterpret_cast<const float4*>(dt + c);
                s += w0.x * q0.x + w0.y * q0.y + w0.z * q0.z + w0.w * q0.w;
                float4 w1 = *reinterpret_cast<const float4*>(Wn + NP + c);
                float4 q1 = *reinterpret_cast<const float4*>(st + c);
                s += w1.x * q1.x + w1.y * q1.y + w1.z * q1.z + w1.w * q1.w;
            }
            wq[g + e] = s;
        }
    }
}

// ---------- score: A via LDS double-buffer (HBM stream), B via register prefetch (L2) ----------
// WG = 4 waves; wave w: t in [t0, t0+64) x n in [w*128, w*128+128)
__global__ __launch_bounds__(256, 2)
void score_kernel(const float* __restrict__ H, const unsigned short* __restrict__ Ub,
                  const float* __restrict__ wq, const float* __restrict__ v_d,
                  float* __restrict__ out) {
    __shared__ unsigned short As[2][64 * 40];   // 64 rows x 32 bf16, stride 40 (16B-aligned, <=2-way banks)
    __shared__ float s_score[64];

    const int tid  = threadIdx.x;
    const int b    = blockIdx.y;
    const int t0   = blockIdx.x * 64;
    const int lane = tid & 63;
    const int w    = tid >> 6;      // n-quadrant
    const int lr   = lane & 15;
    const int lq   = lane >> 4;

    if (tid < 64) s_score[tid] = 0.f;

    // A staging map: thread covers idx = tid, tid+256 : row = idx>>3 (0..63), col4 = (idx&7)*4
    const int r0 = tid >> 3;
    const int r1 = (tid + 256) >> 3;
    const int c4 = (tid & 7) * 4;
    const float* HbA = H + ((size_t)b * NT + t0) * NM;

    const unsigned short* pB = Ub + ((size_t)(w * 128 + lr)) * NM + lq * 8;

    f32x4 acc[4][8];
    #pragma unroll
    for (int i = 0; i < 4; ++i)
        #pragma unroll
        for (int j = 0; j < 8; ++j)
            acc[i][j] = (f32x4){0.f, 0.f, 0.f, 0.f};

    bf16x8 bq[2][8];

    // ---- preload k=0 ----
    {
        float4 f0 = *reinterpret_cast<const float4*>(HbA + (size_t)r0 * NM + c4);
        float4 f1 = *reinterpret_cast<const float4*>(HbA + (size_t)r1 * NM + c4);
        #pragma unroll
        for (int j = 0; j < 8; ++j)
            bq[0][j] = *reinterpret_cast<const bf16x8*>(pB + (size_t)j * 16 * NM);
        *reinterpret_cast<uint2*>(&As[0][r0 * 40 + c4]) = make_uint2(bfpair(f0.x, f0.y), bfpair(f0.z, f0.w));
        *reinterpret_cast<uint2*>(&As[0][r1 * 40 + c4]) = make_uint2(bfpair(f1.x, f1.y), bfpair(f1.z, f1.w));
    }
    __syncthreads();

    #pragma unroll
    for (int kk = 0; kk < 16; ++kk) {
        const int cur = kk & 1;
        const int nxt = cur ^ 1;

        float4 f0, f1;
        if (kk < 15) {
            const int k0 = (kk + 1) * 32;
            // issue A first (so pack's waitcnt leaves B prefetch in flight), then B
            f0 = *reinterpret_cast<const float4*>(HbA + (size_t)r0 * NM + k0 + c4);
            f1 = *reinterpret_cast<const float4*>(HbA + (size_t)r1 * NM + k0 + c4);
            #pragma unroll
            for (int j = 0; j < 8; ++j)
                bq[nxt][j] = *reinterpret_cast<const bf16x8*>(pB + (size_t)j * 16 * NM + k0);
        }

        bf16x8 a[4];
        #pragma unroll
        for (int i = 0; i < 4; ++i)
            a[i] = *reinterpret_cast<const bf16x8*>(&As[cur][(i * 16 + lr) * 40 + lq * 8]);

        #pragma unroll
        for (int i = 0; i < 4; ++i)
            #pragma unroll
            for (int j = 0; j < 8; ++j)
                acc[i][j] = __builtin_amdgcn_mfma_f32_16x16x32_bf16(a[i], bq[cur][j], acc[i][j], 0, 0, 0);

        if (kk < 15) {
            *reinterpret_cast<uint2*>(&As[nxt][r0 * 40 + c4]) = make_uint2(bfpair(f0.x, f0.y), bfpair(f0.z, f0.w));
            *reinterpret_cast<uint2*>(&As[nxt][r1 * 40 + c4]) = make_uint2(bfpair(f1.x, f1.y), bfpair(f1.z, f1.w));
            __syncthreads();
        }
    }

    // ---- epilogue: C/D layout col(n) = lr (+j*16+w*128), row(t) = i*16 + lq*4 + reg ----
    const float* wqb = wq + (size_t)b * NM;
    float vv[8], wv[8];
    #pragma unroll
    for (int j = 0; j < 8; ++j) {
        int n = w * 128 + j * 16 + lr;
        vv[j] = v_d[n];
        wv[j] = wqb[n];
    }
    #pragma unroll
    for (int i = 0; i < 4; ++i) {
        #pragma unroll
        for (int r = 0; r < 4; ++r) {
            float s = 0.f;
            #pragma unroll
            for (int j = 0; j < 8; ++j)
                s += vv[j] * fast_tanh(wv[j] + acc[i][j][r]);
            #pragma unroll
            for (int off = 1; off < 16; off <<= 1)
                s += __shfl_xor(s, off, 64);
            if (lr == 0) atomicAdd(&s_score[i * 16 + lq * 4 + r], s);
        }
    }
    __syncthreads();
    if (tid < 64) out[(size_t)b * NT + t0 + tid] = s_score[tid];
}

// ---------- softmax over T=1024, in place, one WG per b ----------
__global__ void softmax_kernel(float* __restrict__ out) {
    const int b   = blockIdx.x;
    const int tid = threadIdx.x;          // 256 threads x 4 elems
    float* p = out + (size_t)b * NT;
    float4 v = reinterpret_cast<float4*>(p)[tid];
    float m = fmaxf(fmaxf(v.x, v.y), fmaxf(v.z, v.w));
    #pragma unroll
    for (int off = 32; off >= 1; off >>= 1)
        m = fmaxf(m, __shfl_xor(m, off, 64));
    __shared__ float red[8];
    const int wv = tid >> 6;
    if ((tid & 63) == 0) red[wv] = m;
    __syncthreads();
    m = fmaxf(fmaxf(red[0], red[1]), fmaxf(red[2], red[3]));
    float e0 = __expf(v.x - m), e1 = __expf(v.y - m);
    float e2 = __expf(v.z - m), e3 = __expf(v.w - m);
    float s = e0 + e1 + e2 + e3;
    #pragma unroll
    for (int off = 32; off >= 1; off >>= 1)
        s += __shfl_xor(s, off, 64);
    if ((tid & 63) == 0) red[4 + wv] = s;
    __syncthreads();
    s = red[4] + red[5] + red[6] + red[7];
    float inv = 1.f / s;
    float4 o;
    o.x = e0 * inv; o.y = e1 * inv; o.z = e2 * inv; o.w = e3 * inv;
    reinterpret_cast<float4*>(p)[tid] = o;
}

extern "C" void kernel_launch(void* const* d_in, const int* in_sizes, int n_in,
                              void* d_out, int out_size, void* d_ws, size_t ws_size,
                              hipStream_t stream) {
    const float* d_t = (const float*)d_in[0];
    const float* s_t = (const float*)d_in[1];
    const float* H   = (const float*)d_in[2];
    // d_in[3] = T (scalar, 1024) — shapes hard-coded
    const float* W_d = (const float*)d_in[4];
    const float* U_d = (const float*)d_in[5];
    const float* v_d = (const float*)d_in[6];
    float* out = (float*)d_out;

    unsigned short* Ub = (unsigned short*)d_ws;              // 512 KB bf16 U
    float* wq = (float*)((char*)d_ws + 512 * 1024);          // 256 KB fp32 wq

    prep_kernel<<<384, 256, 0, stream>>>(U_d, Ub, d_t, s_t, W_d, wq);
    score_kernel<<<dim3(NT / 64, NB), 256, 0, stream>>>(H, Ub, wq, v_d, out);
    softmax_kernel<<<NB, 256, 0, stream>>>(out);
}

// Round 4
// 467.026 us; speedup vs baseline: 1.2574x; 1.0882x over previous
//
#include <hip/hip_runtime.h>
#include <hip/hip_bf16.h>
#include <stdint.h>

// Problem constants: M=512, P=256, B=128, T=1024
#define NB   128
#define NT   1024
#define NM   512
#define NP   256

typedef __attribute__((ext_vector_type(8))) short bf16x8;
typedef __attribute__((ext_vector_type(4))) float f32x4;
typedef unsigned int u32;

// pack two f32 -> two bf16 in one u32 (round-half-up; bias << bf16 ulp)
__device__ __forceinline__ uint32_t bfpair(float a, float b) {
    uint32_t ua = __float_as_uint(a) + 0x8000u;
    uint32_t ub = __float_as_uint(b) + 0x8000u;
    return __builtin_amdgcn_perm(ub, ua, 0x07060302u);
}

__device__ __forceinline__ bf16x8 pack8(float4 lo, float4 hi) {
    union { bf16x8 v; uint32_t u[4]; } r;
    r.u[0] = bfpair(lo.x, lo.y);
    r.u[1] = bfpair(lo.z, lo.w);
    r.u[2] = bfpair(hi.x, hi.y);
    r.u[3] = bfpair(hi.z, hi.w);
    return r.v;
}

__device__ __forceinline__ float fast_tanh(float x) {
    float e = __expf(2.0f * x);                       // inf-safe
    return 1.0f - 2.0f * __builtin_amdgcn_rcpf(e + 1.0f);
}

// async global->LDS DMA, 16 B per lane; LDS dest = wave-uniform base + lane*16
typedef const __attribute__((address_space(1))) u32* gas_t;
typedef __attribute__((address_space(3))) u32* las_t;
__device__ __forceinline__ void dma16(const void* g, void* l) {
    __builtin_amdgcn_global_load_lds((gas_t)g, (las_t)l, 16, 0, 0);
}

// ---------- prep: 0..255 cvt U->bf16 | 256..383 wq GEMV | 384..511 zero d_out ----------
__global__ void prep_kernel(const float* __restrict__ U, unsigned short* __restrict__ Ub,
                            const float* __restrict__ d_t, const float* __restrict__ s_t,
                            const float* __restrict__ W, float* __restrict__ wq,
                            float* __restrict__ out) {
    const int bx = blockIdx.x;
    if (bx < 256) {
        int idx = bx * 256 + threadIdx.x;                  // 65536 threads, 1 float4 each
        float4 u = reinterpret_cast<const float4*>(U)[idx];
        reinterpret_cast<uint2*>(Ub)[idx] = make_uint2(bfpair(u.x, u.y), bfpair(u.z, u.w));
    } else if (bx < 384) {
        int g = (bx - 256) * 512 + threadIdx.x * 2;        // 2 outputs/thread -> 65536
        int b = g >> 9;
        const float* dt = d_t + (size_t)b * NP;
        const float* st = s_t + (size_t)b * NP;
        #pragma unroll
        for (int e = 0; e < 2; ++e) {
            int n = (g + e) & 511;
            const float* Wn = W + (size_t)n * 512;
            float s = 0.f;
            #pragma unroll 4
            for (int c = 0; c < NP; c += 4) {
                float4 w0 = *reinterpret_cast<const float4*>(Wn + c);
                float4 q0 = *reinterpret_cast<const float4*>(dt + c);
                s += w0.x * q0.x + w0.y * q0.y + w0.z * q0.z + w0.w * q0.w;
                float4 w1 = *reinterpret_cast<const float4*>(Wn + NP + c);
                float4 q1 = *reinterpret_cast<const float4*>(st + c);
                s += w1.x * q1.x + w1.y * q1.y + w1.z * q1.z + w1.w * q1.w;
            }
            wq[g + e] = s;
        }
    } else {
        int idx = (bx - 384) * 256 + threadIdx.x;          // 32768 float4 = 128K floats
        reinterpret_cast<float4*>(out)[idx] = make_float4(0.f, 0.f, 0.f, 0.f);
    }
}

// ---------- score: 128t x 256n per WG, global_load_lds dbuf, 1 barrier/iter ----------
// grid 2048 1-D, swizzled: g=id>>4, p=id&7, nh=(id>>3)&1; tile=g*8+p (tt=tile&7, b=tile>>3)
// -> both nh of a tile get ids differing by 8 => same XCD (id%8) => share H lines in L2.
// waves: w>>1 = t-half (64 rows), w&1 = n-half (128 cols). acc 4x8 f32x4 = 128 AGPR.
__global__ __launch_bounds__(256, 2)
void score_kernel(const float* __restrict__ H, const unsigned short* __restrict__ Ub,
                  const float* __restrict__ wq, const float* __restrict__ v_d,
                  float* __restrict__ out) {
    __shared__ float          As[2][128 * 32];     // 16 KB/buf, row=128 B, chunk-swizzled
    __shared__ unsigned short Bs[2][256 * 32];     // 16 KB/buf, row= 64 B, chunk-swizzled
    __shared__ float s_score[128];

    const int tid  = threadIdx.x;
    const int id   = blockIdx.x;
    const int tile = (id >> 4) * 8 + (id & 7);
    const int nh   = (id >> 3) & 1;
    const int tt   = tile & 7;
    const int b    = tile >> 3;

    const int lane = tid & 63;
    const int w    = tid >> 6;
    const int lr   = lane & 15;
    const int lq   = lane >> 4;
    const int tw   = w >> 1;
    const int nw   = w & 1;

    if (tid < 128) s_score[tid] = 0.f;

    // per-lane DMA sources. A: instr q covers rows w*32+q*8+(lane>>3); slot c=lane&7 holds
    // global chunk c^(r&7). B: rows w*64+q*16+(lane>>2); slot c=lane&3 holds chunk c^((r>>1)&3).
    const float* gA[4];
    const unsigned short* gB[4];
    unsigned lL[4];
    #pragma unroll
    for (int q = 0; q < 4; ++q) {
        int rA = w * 32 + q * 8 + (lane >> 3);
        int cA = (lane & 7) ^ (rA & 7);
        gA[q] = H + ((size_t)(b * NT + tt * 128 + rA)) * NM + cA * 4;
        int rB = w * 64 + q * 16 + (lane >> 2);
        int cB = (lane & 3) ^ ((rB >> 1) & 3);
        gB[q] = Ub + ((size_t)(nh * 256 + rB)) * NM + cB * 8;
        lL[q] = (unsigned)((w * 4 + q) * 1024 + lane * 16);
    }

    f32x4 acc[4][8];
    #pragma unroll
    for (int i = 0; i < 4; ++i)
        #pragma unroll
        for (int j = 0; j < 8; ++j)
            acc[i][j] = (f32x4){0.f, 0.f, 0.f, 0.f};

    // preload k-chunk 0 into buf 0
    #pragma unroll
    for (int q = 0; q < 4; ++q) dma16(gA[q], (char*)As[0] + lL[q]);
    #pragma unroll
    for (int q = 0; q < 4; ++q) dma16(gB[q], (char*)Bs[0] + lL[q]);

    #pragma unroll
    for (int kk = 0; kk < 16; ++kk) {
        const int cur = kk & 1;
        const int nxt = cur ^ 1;
        // barrier: (a) drains cur's DMA (issued last iter), (b) everyone done reading buf nxt
        __syncthreads();
        if (kk < 15) {
            #pragma unroll
            for (int q = 0; q < 4; ++q) { gA[q] += 32; dma16(gA[q], (char*)As[nxt] + lL[q]); }
            #pragma unroll
            for (int q = 0; q < 4; ++q) { gB[q] += 32; dma16(gB[q], (char*)Bs[nxt] + lL[q]); }
        }

        bf16x8 a[4];
        #pragma unroll
        for (int i = 0; i < 4; ++i) {
            int t_loc = tw * 64 + i * 16 + lr;
            int s = t_loc & 7;
            const char* base = (const char*)As[cur] + t_loc * 128;
            float4 lo = *reinterpret_cast<const float4*>(base + (((2 * lq)     ^ s) * 16));
            float4 hi = *reinterpret_cast<const float4*>(base + (((2 * lq + 1) ^ s) * 16));
            a[i] = pack8(lo, hi);
        }
        bf16x8 bb[8];
        #pragma unroll
        for (int j = 0; j < 8; ++j) {
            int n_loc = nw * 128 + j * 16 + lr;
            int slot = lq ^ ((n_loc >> 1) & 3);
            bb[j] = *reinterpret_cast<const bf16x8*>((const char*)Bs[cur] + n_loc * 64 + slot * 16);
        }

        #pragma unroll
        for (int i = 0; i < 4; ++i)
            #pragma unroll
            for (int j = 0; j < 8; ++j)
                acc[i][j] = __builtin_amdgcn_mfma_f32_16x16x32_bf16(a[i], bb[j], acc[i][j], 0, 0, 0);
    }

    // epilogue: acc[i][j][r] at t = tt*128 + tw*64 + i*16 + lq*4 + r, n = nh*256 + nw*128 + j*16 + lr
    const float* wqb = wq + (size_t)b * NM;
    float vv[8], wv[8];
    #pragma unroll
    for (int j = 0; j < 8; ++j) {
        int n = nh * 256 + nw * 128 + j * 16 + lr;
        vv[j] = v_d[n];
        wv[j] = wqb[n];
    }
    #pragma unroll
    for (int i = 0; i < 4; ++i) {
        #pragma unroll
        for (int r = 0; r < 4; ++r) {
            float s = 0.f;
            #pragma unroll
            for (int j = 0; j < 8; ++j)
                s += vv[j] * fast_tanh(wv[j] + acc[i][j][r]);
            #pragma unroll
            for (int off = 1; off < 16; off <<= 1)
                s += __shfl_xor(s, off, 64);
            if (lr == 0) atomicAdd(&s_score[tw * 64 + i * 16 + lq * 4 + r], s);
        }
    }
    __syncthreads();
    if (tid < 128) atomicAdd(&out[(size_t)b * NT + tt * 128 + tid], s_score[tid]);
}

// ---------- softmax over T=1024, in place, one WG per b ----------
__global__ void softmax_kernel(float* __restrict__ out) {
    const int b   = blockIdx.x;
    const int tid = threadIdx.x;          // 256 threads x 4 elems
    float* p = out + (size_t)b * NT;
    float4 v = reinterpret_cast<float4*>(p)[tid];
    float m = fmaxf(fmaxf(v.x, v.y), fmaxf(v.z, v.w));
    #pragma unroll
    for (int off = 32; off >= 1; off >>= 1)
        m = fmaxf(m, __shfl_xor(m, off, 64));
    __shared__ float red[8];
    const int wv = tid >> 6;
    if ((tid & 63) == 0) red[wv] = m;
    __syncthreads();
    m = fmaxf(fmaxf(red[0], red[1]), fmaxf(red[2], red[3]));
    float e0 = __expf(v.x - m), e1 = __expf(v.y - m);
    float e2 = __expf(v.z - m), e3 = __expf(v.w - m);
    float s = e0 + e1 + e2 + e3;
    #pragma unroll
    for (int off = 32; off >= 1; off >>= 1)
        s += __shfl_xor(s, off, 64);
    if ((tid & 63) == 0) red[4 + wv] = s;
    __syncthreads();
    s = red[4] + red[5] + red[6] + red[7];
    float inv = 1.f / s;
    float4 o;
    o.x = e0 * inv; o.y = e1 * inv; o.z = e2 * inv; o.w = e3 * inv;
    reinterpret_cast<float4*>(p)[tid] = o;
}

extern "C" void kernel_launch(void* const* d_in, const int* in_sizes, int n_in,
                              void* d_out, int out_size, void* d_ws, size_t ws_size,
                              hipStream_t stream) {
    const float* d_t = (const float*)d_in[0];
    const float* s_t = (const float*)d_in[1];
    const float* H   = (const float*)d_in[2];
    // d_in[3] = T (scalar, 1024) — shapes hard-coded
    const float* W_d = (const float*)d_in[4];
    const float* U_d = (const float*)d_in[5];
    const float* v_d = (const float*)d_in[6];
    float* out = (float*)d_out;

    unsigned short* Ub = (unsigned short*)d_ws;              // 512 KB bf16 U
    float* wq = (float*)((char*)d_ws + 512 * 1024);          // 256 KB fp32 wq

    prep_kernel<<<512, 256, 0, stream>>>(U_d, Ub, d_t, s_t, W_d, wq, out);
    score_kernel<<<2048, 256, 0, stream>>>(H, Ub, wq, v_d, out);
    softmax_kernel<<<NB, 256, 0, stream>>>(out);
}